// Round 1
// baseline (368.869 us; speedup 1.0000x reference)
//
#include <hip/hip_runtime.h>

// NestedMoEModel: B=32768, D=256, H=256, G=8, E=8.
// Key reductions (see round-0 theory):
//  1) softmax row-sum == 1  =>  gate branch drops out entirely.
//  2) einsum("bi,gehi->bgh") = x @ (sum_e W_exp)^T  => single GEMM
//     M=32768, N=G*H=2048, K=D=256, + bias sum_e b_exp.
// Pipeline: prep kernel folds W_exp->Wsum(bf16, [N][K]), b_exp->bsum(f32),
// x->bf16; then m97-style MFMA GEMM (128x128 tile, BK=32, global_load_lds x16).

typedef unsigned short u16;
typedef __bf16 bf16x8 __attribute__((ext_vector_type(8)));
typedef float f32x4 __attribute__((ext_vector_type(4)));

#define MB 32768   // batch (GEMM M)
#define NN 2048    // G*H   (GEMM N)
#define KK 256     // D     (GEMM K)

__device__ __forceinline__ u16 f2bf(float f) {
    // round-to-nearest-even fp32 -> bf16 (inputs finite)
    unsigned u = __builtin_bit_cast(unsigned, f);
    u += 0x7FFFu + ((u >> 16) & 1u);
    return (u16)(u >> 16);
}

__device__ __forceinline__ void gld16(const void* g, void* l) {
    // async global->LDS, 16B/lane; LDS dest must be wave-uniform base + lane*16
    __builtin_amdgcn_global_load_lds((const __attribute__((address_space(1))) void*)g,
                                     (__attribute__((address_space(3))) void*)l,
                                     16, 0, 0);
}

// ---------------- prep: Wsum/bsum fold + x fp32->bf16 ----------------
// blocks [0,512):   Wsum[n][i] = sum_e W_exp[g][e][h][i] (n = g*256+h), bf16
// blocks [512,2560): x -> bf16 (2,097,152 float4s, 4 per thread)
__global__ __launch_bounds__(256) void prep_kernel(
    const float* __restrict__ x, const float* __restrict__ Wexp,
    const float* __restrict__ bexp, u16* __restrict__ xb,
    u16* __restrict__ Ws, float* __restrict__ bs)
{
    const int blk = blockIdx.x;
    const int t = threadIdx.x;
    if (blk < 512) {
        const int tid = blk * 256 + t;        // 0..131071
        const int n = tid >> 6;               // 0..2047
        const int i = (tid & 63) << 2;        // 0..252
        const int g = n >> 8, h = n & 255;
        const float* base = Wexp + ((size_t)(g * 8) * 256 + h) * 256 + i;
        float s0 = 0.f, s1 = 0.f, s2 = 0.f, s3 = 0.f;
#pragma unroll
        for (int e = 0; e < 8; ++e) {
            const float4 v = *(const float4*)(base + (size_t)e * 65536);
            s0 += v.x; s1 += v.y; s2 += v.z; s3 += v.w;
        }
        ushort4 o;
        o.x = f2bf(s0); o.y = f2bf(s1); o.z = f2bf(s2); o.w = f2bf(s3);
        *(ushort4*)(Ws + (size_t)n * KK + i) = o;
        if ((tid & 63) == 0) {
            float sb = 0.f;
#pragma unroll
            for (int e = 0; e < 8; ++e) sb += bexp[(g * 8 + e) * 256 + h];
            bs[n] = sb;
        }
    } else {
        int idx = (blk - 512) * 256 + t;      // 0..524287
        const float4* xv = (const float4*)x;
#pragma unroll
        for (int it = 0; it < 4; ++it) {
            const int j = idx + it * 524288;
            const float4 v = xv[j];
            ushort4 o;
            o.x = f2bf(v.x); o.y = f2bf(v.y); o.z = f2bf(v.z); o.w = f2bf(v.w);
            *(ushort4*)(xb + (size_t)j * 4) = o;
        }
    }
}

// ---------------- GEMM: C[M][N] = A[M][K] * Bt[N][K]^T + bias[N] ----------------
// 128x128 tile, BK=32, 256 threads = 4 waves (2x2 of 64x64), 16x16x32 bf16 MFMA.
__global__ __launch_bounds__(256) void gemm_kernel(
    const u16* __restrict__ A, const u16* __restrict__ Bt,
    const float* __restrict__ bias, float* __restrict__ C)
{
    __shared__ __align__(16) u16 sA[128 * 32];
    __shared__ __align__(16) u16 sB[128 * 32];

    const int t = threadIdx.x;
    const int m0 = blockIdx.x * 128;
    const int n0 = blockIdx.y * 128;

    const int lane = t & 63;
    const int w = t >> 6;
    const int wm = (w & 1) << 6;   // wave row offset in tile
    const int wn = (w >> 1) << 6;  // wave col offset in tile
    const int lr = lane & 15;
    const int quad = lane >> 4;

    f32x4 acc[4][4] = {};

    // staging: thread t covers (row = t>>2, 16B chunk = t&3); 2 issues -> 128 rows
    const int srow = t >> 2;
    const int sk = (t & 3) << 3;   // element offset in row
    const u16* Ag = A + (size_t)(m0 + srow) * KK + sk;
    const u16* Bg = Bt + (size_t)(n0 + srow) * KK + sk;
    u16* lA = sA + t * 8;          // byte offset t*16: wave-uniform + lane*16
    u16* lB = sB + t * 8;

    for (int k0 = 0; k0 < KK; k0 += 32) {
        gld16(Ag + k0, lA);
        gld16(Ag + (size_t)64 * KK + k0, lA + 64 * 32);
        gld16(Bg + k0, lB);
        gld16(Bg + (size_t)64 * KK + k0, lB + 64 * 32);
        __syncthreads();   // compiler emits s_waitcnt vmcnt(0) before s_barrier

        bf16x8 af[4], bfr[4];
#pragma unroll
        for (int mi = 0; mi < 4; ++mi)
            af[mi] = *(const bf16x8*)(sA + (wm + mi * 16 + lr) * 32 + quad * 8);
#pragma unroll
        for (int ni = 0; ni < 4; ++ni)
            bfr[ni] = *(const bf16x8*)(sB + (wn + ni * 16 + lr) * 32 + quad * 8);
#pragma unroll
        for (int mi = 0; mi < 4; ++mi)
#pragma unroll
            for (int ni = 0; ni < 4; ++ni)
                acc[mi][ni] = __builtin_amdgcn_mfma_f32_16x16x32_bf16(
                    af[mi], bfr[ni], acc[mi][ni], 0, 0, 0);
        __syncthreads();
    }

    // epilogue: C/D layout col=lane&15, row=quad*4+reg  (m89-verified)
#pragma unroll
    for (int ni = 0; ni < 4; ++ni) {
        const int col = n0 + wn + ni * 16 + lr;
        const float bv = bias[col];
#pragma unroll
        for (int mi = 0; mi < 4; ++mi) {
            const int row = m0 + wm + mi * 16 + quad * 4;
            float* Cp = C + (size_t)row * NN + col;
#pragma unroll
            for (int r = 0; r < 4; ++r)
                Cp[(size_t)r * NN] = acc[mi][ni][r] + bv;
        }
    }
}

extern "C" void kernel_launch(void* const* d_in, const int* in_sizes, int n_in,
                              void* d_out, int out_size, void* d_ws, size_t ws_size,
                              hipStream_t stream) {
    const float* x    = (const float*)d_in[0];
    // d_in[1] = W_gate, d_in[2] = b_gate: unused (softmax row-sum == 1)
    const float* Wexp = (const float*)d_in[3];
    const float* bexp = (const float*)d_in[4];
    float* out = (float*)d_out;

    // workspace layout (needs ~17.9 MB)
    u16*   xb = (u16*)d_ws;                                   // 16 MB  x as bf16
    u16*   Ws = (u16*)((char*)d_ws + (size_t)16777216);       // 1 MB   Wsum bf16 [N][K]
    float* bs = (float*)((char*)d_ws + (size_t)16777216 + 1048576); // 8 KB bsum

    prep_kernel<<<2560, 256, 0, stream>>>(x, Wexp, bexp, xb, Ws, bs);
    dim3 grid(MB / 128, NN / 128);  // (256, 16)
    gemm_kernel<<<grid, 256, 0, stream>>>(xb, Ws, bs, out);
}

// Round 2
// 336.272 us; speedup vs baseline: 1.0969x; 1.0969x over previous
//
#include <hip/hip_runtime.h>

// NestedMoEModel: B=32768, D=256, H=256, G=8, E=8.
// Reductions: softmax row-sum == 1 => gate branch drops; sum_e is linear =>
// single GEMM  out[32768,2048] = x @ (sum_e W_exp)^T + sum_e b_exp.
// R2: BK=64 (4 K-iters, fewer barrier drains), XOR-swizzled LDS (conflict-free
// ds_read_b128), grid n-fastest for A-tile L2 reuse.

typedef unsigned short u16;
typedef __bf16 bf16x8 __attribute__((ext_vector_type(8)));
typedef float f32x4 __attribute__((ext_vector_type(4)));

#define MB 32768   // batch (GEMM M)
#define NN 2048    // G*H   (GEMM N)
#define KK 256     // D     (GEMM K)
#define BK 64

__device__ __forceinline__ u16 f2bf(float f) {
    unsigned u = __builtin_bit_cast(unsigned, f);
    u += 0x7FFFu + ((u >> 16) & 1u);
    return (u16)(u >> 16);
}

__device__ __forceinline__ void gld16(const void* g, void* l) {
    // async global->LDS, 16B/lane; LDS dest must be wave-uniform base + lane*16
    __builtin_amdgcn_global_load_lds((const __attribute__((address_space(1))) void*)g,
                                     (__attribute__((address_space(3))) void*)l,
                                     16, 0, 0);
}

// ---------------- prep: Wsum/bsum fold + x fp32->bf16 ----------------
__global__ __launch_bounds__(256) void prep_kernel(
    const float* __restrict__ x, const float* __restrict__ Wexp,
    const float* __restrict__ bexp, u16* __restrict__ xb,
    u16* __restrict__ Ws, float* __restrict__ bs)
{
    const int blk = blockIdx.x;
    const int t = threadIdx.x;
    if (blk < 512) {
        const int tid = blk * 256 + t;        // 0..131071
        const int n = tid >> 6;               // 0..2047
        const int i = (tid & 63) << 2;        // 0..252
        const int g = n >> 8, h = n & 255;
        const float* base = Wexp + ((size_t)(g * 8) * 256 + h) * 256 + i;
        float s0 = 0.f, s1 = 0.f, s2 = 0.f, s3 = 0.f;
#pragma unroll
        for (int e = 0; e < 8; ++e) {
            const float4 v = *(const float4*)(base + (size_t)e * 65536);
            s0 += v.x; s1 += v.y; s2 += v.z; s3 += v.w;
        }
        ushort4 o;
        o.x = f2bf(s0); o.y = f2bf(s1); o.z = f2bf(s2); o.w = f2bf(s3);
        *(ushort4*)(Ws + (size_t)n * KK + i) = o;
        if ((tid & 63) == 0) {
            float sb = 0.f;
#pragma unroll
            for (int e = 0; e < 8; ++e) sb += bexp[(g * 8 + e) * 256 + h];
            bs[n] = sb;
        }
    } else {
        int idx = (blk - 512) * 256 + t;      // 0..524287
        const float4* xv = (const float4*)x;
#pragma unroll
        for (int it = 0; it < 4; ++it) {
            const int j = idx + it * 524288;
            const float4 v = xv[j];
            ushort4 o;
            o.x = f2bf(v.x); o.y = f2bf(v.y); o.z = f2bf(v.z); o.w = f2bf(v.w);
            *(ushort4*)(xb + (size_t)j * 4) = o;
        }
    }
}

// ---------------- GEMM: C = A * Bt^T + bias ----------------
// 128x128 tile, BK=64, 4 waves (2x2 of 64x64), 16x16x32 bf16 MFMA.
// LDS layout: row-major 128 x 64, but each row's eight 8-elem chunks are
// permuted by chunk^(row&7). Staging applies the permutation on the GLOBAL
// source address (glds LDS dest is forced to base+lane*16); fragment reads
// then land 2-way bank-aliased (free) instead of 8-way.
__global__ __launch_bounds__(256, 3) void gemm_kernel(
    const u16* __restrict__ A, const u16* __restrict__ Bt,
    const float* __restrict__ bias, float* __restrict__ C)
{
    __shared__ __align__(16) u16 sA[128 * BK];
    __shared__ __align__(16) u16 sB[128 * BK];

    const int t = threadIdx.x;
    const int n0 = blockIdx.x * 128;   // x fastest: 16 consecutive blocks share A-tile
    const int m0 = blockIdx.y * 128;

    const int lane = t & 63;
    const int w = t >> 6;
    const int wm = (w & 1) << 6;
    const int wn = (w >> 1) << 6;
    const int lr = lane & 15;
    const int quad = lane >> 4;

    f32x4 acc[4][4] = {};

    // staging: 4 rounds per operand; slot = r*256+t -> row = slot>>3, cs = slot&7
    const int srow = t >> 3;
    const int scs  = t & 7;

    for (int k0 = 0; k0 < KK; k0 += BK) {
#pragma unroll
        for (int r = 0; r < 4; ++r) {
            const int row = srow + r * 32;
            const int gc  = ((scs ^ (row & 7)) << 3);   // swizzled element offset
            gld16(A  + (size_t)(m0 + row) * KK + k0 + gc, sA + (size_t)(r * 256 + t) * 8);
            gld16(Bt + (size_t)(n0 + row) * KK + k0 + gc, sB + (size_t)(r * 256 + t) * 8);
        }
        __syncthreads();

#pragma unroll
        for (int kk = 0; kk < 2; ++kk) {
            bf16x8 af[4], bf[4];
#pragma unroll
            for (int mi = 0; mi < 4; ++mi) {
                const int rr = wm + mi * 16 + lr;
                const int c  = (kk * 4 + quad) ^ (rr & 7);
                af[mi] = *(const bf16x8*)(sA + rr * BK + (c << 3));
            }
#pragma unroll
            for (int ni = 0; ni < 4; ++ni) {
                const int rr = wn + ni * 16 + lr;
                const int c  = (kk * 4 + quad) ^ (rr & 7);
                bf[ni] = *(const bf16x8*)(sB + rr * BK + (c << 3));
            }
#pragma unroll
            for (int mi = 0; mi < 4; ++mi)
#pragma unroll
                for (int ni = 0; ni < 4; ++ni)
                    acc[mi][ni] = __builtin_amdgcn_mfma_f32_16x16x32_bf16(
                        af[mi], bf[ni], acc[mi][ni], 0, 0, 0);
        }
        __syncthreads();
    }

    // epilogue: C/D layout col=lane&15, row=quad*4+reg (m89-verified)
#pragma unroll
    for (int ni = 0; ni < 4; ++ni) {
        const int col = n0 + wn + ni * 16 + lr;
        const float bv = bias[col];
#pragma unroll
        for (int mi = 0; mi < 4; ++mi) {
            const int row = m0 + wm + mi * 16 + quad * 4;
            float* Cp = C + (size_t)row * NN + col;
#pragma unroll
            for (int r = 0; r < 4; ++r)
                Cp[(size_t)r * NN] = acc[mi][ni][r] + bv;
        }
    }
}

extern "C" void kernel_launch(void* const* d_in, const int* in_sizes, int n_in,
                              void* d_out, int out_size, void* d_ws, size_t ws_size,
                              hipStream_t stream) {
    const float* x    = (const float*)d_in[0];
    // d_in[1] = W_gate, d_in[2] = b_gate: unused (softmax row-sum == 1)
    const float* Wexp = (const float*)d_in[3];
    const float* bexp = (const float*)d_in[4];
    float* out = (float*)d_out;

    u16*   xb = (u16*)d_ws;                                         // 16 MB
    u16*   Ws = (u16*)((char*)d_ws + (size_t)16777216);             // 1 MB
    float* bs = (float*)((char*)d_ws + (size_t)16777216 + 1048576); // 8 KB

    prep_kernel<<<2560, 256, 0, stream>>>(x, Wexp, bexp, xb, Ws, bs);
    dim3 grid(NN / 128, MB / 128);  // (16, 256) — n fastest
    gemm_kernel<<<grid, 256, 0, stream>>>(xb, Ws, bs, out);
}